// Round 8
// baseline (501.291 us; speedup 1.0000x reference)
//
#include <hip/hip_runtime.h>
#include <stdint.h>

// Inputs are FP32 (proven R4-R7 pass/fail matrix); output is FP32.
#define DIM 1536
#define SLEN 3900
#define SPAD 3904   // padded V^T row stride (16B-aligned rows)
#define NH 12
#define HD 128
#define SKP 136     // fallback attn sK row stride (elems)
#define SVP 68      // fallback attn sV/sP row stride (elems)
#define KSPLIT 1984 // KV split point: 31 tiles / 30 tiles

typedef __bf16 bf16x8 __attribute__((ext_vector_type(8)));
typedef float f32x4 __attribute__((ext_vector_type(4)));

__device__ __forceinline__ float b2f(uint16_t u) {
  union { uint32_t i; float f; } x; x.i = ((uint32_t)u) << 16; return x.f;
}
// hardware RNE convert
__device__ __forceinline__ uint16_t f2b(float f) {
  union { __bf16 h; uint16_t u; } c; c.h = (__bf16)f; return c.u;
}
__device__ __forceinline__ bf16x8 ld8bf(const uint16_t* p) {
  bf16x8 r; __builtin_memcpy(&r, p, 16); return r;
}
__device__ __forceinline__ void st8(uint16_t* p, bf16x8 v) {
  __builtin_memcpy(p, &v, 16);
}
// async global->LDS, 16B/lane; LDS dest = wave-uniform base + lane*16 (m97/m104)
__device__ __forceinline__ void gl_lds16(const void* g, void* l) {
  __builtin_amdgcn_global_load_lds((__attribute__((address_space(1))) void*)(g),
                                   (__attribute__((address_space(3))) void*)(l),
                                   16, 0, 0);
}
// G4 XOR-swizzled LDS addressing (unpadded rows; byte ^= (row&7)<<4).
// 256B-row variant (sK: 128 bf16/row) and 128B-row variant (sV/sP: 64 bf16/row).
__device__ __forceinline__ uint16_t* swz256(uint16_t* b, int row, int ce) {
  return (uint16_t*)((char*)b + row * 256 + ((ce * 2) ^ ((row & 7) << 4)));
}
__device__ __forceinline__ uint16_t* swz128(uint16_t* b, int row, int ce) {
  return (uint16_t*)((char*)b + row * 128 + ((ce * 2) ^ ((row & 7) << 4)));
}

// ------------------------------------------------ x: fp32 -> bf16 (one pass)
__global__ __launch_bounds__(256) void conv_x(
    const float* __restrict__ x, uint16_t* __restrict__ xb) {
  int i = (blockIdx.x * 256 + threadIdx.x) * 8;  // n divisible by 8
  float a[8];
  __builtin_memcpy(a, x + i, 32);
  uint16_t t[8];
#pragma unroll
  for (int q = 0; q < 8; q++) t[q] = f2b(a[q]);
  __builtin_memcpy(xb + i, t, 16);
}

// --------------------- transpose all 4 W: fp32 in -> bf16^T out (z selects)
__global__ __launch_bounds__(256) void transposeW4(
    const float* __restrict__ w0, const float* __restrict__ w1,
    const float* __restrict__ w2, const float* __restrict__ w3,
    uint16_t* __restrict__ WT4) {
  __shared__ uint16_t t[32][33];
  const int z = blockIdx.z;
  const float* src = z == 0 ? w0 : z == 1 ? w1 : z == 2 ? w2 : w3;
  uint16_t* dst = WT4 + (size_t)z * DIM * DIM;
  const int bx = blockIdx.x * 32, by = blockIdx.y * 32;
  const int tx = threadIdx.x & 31, ty = threadIdx.x >> 5;  // ty 0..7
#pragma unroll
  for (int i = 0; i < 32; i += 8)
    t[ty + i][tx] = f2b(src[(size_t)(by + ty + i) * DIM + bx + tx]);
  __syncthreads();
#pragma unroll
  for (int i = 0; i < 32; i += 8)
    dst[(size_t)(bx + ty + i) * DIM + by + tx] = t[tx][ty + i];
}

// ------------------------------------------------- GEMM: C = A * BT^T (+bias)
// gl_lds staging (m97 idiom): unpadded 64B-pitch LDS (required: lane-ordered
// dest). R17: TWO BK=32 subtiles staged per barrier round (sA/sB doubled,
// 32KB LDS) -> one vmcnt(0)+barrier-pair per 64 K (24 drains vs 48), 32 MFMA
// per drain. Same layout/frag reads/VGPR as the proven BK=32 body.
// mode 1: z selects BT slice + head-split bf16 out Cb. mode 0: fp32 out + bias.
__global__ __launch_bounds__(256) void gemm(
    const uint16_t* __restrict__ A, const uint16_t* __restrict__ BT4,
    uint16_t* __restrict__ Cb, float* __restrict__ Cf,
    const float* __restrict__ bias, int M, int mode) {
  __shared__ __align__(16) uint16_t sA[2][128 * 32];
  __shared__ __align__(16) uint16_t sB[2][128 * 32];
  const int z = blockIdx.z;
  const uint16_t* BT = BT4 + (size_t)z * DIM * DIM;
  const int m0 = blockIdx.x * 128;
  const int n0 = blockIdx.y * 128;
  const int tid = threadIdx.x;
  const int wave = tid >> 6, lane = tid & 63;
  const int mh = (wave >> 1) * 64, nh = (wave & 1) * 64;
  const int lr = lane >> 2, lc = (lane & 3) * 8;  // staging row/col in 16-row slab
  const int r0 = wave * 32;                       // staging slab base row
  const int fm = mh + (lane & 15);
  const int fn = nh + (lane & 15);
  const int ko = (lane >> 4) * 8;

  f32x4 acc[4][4];
  const f32x4 z4 = {0.f, 0.f, 0.f, 0.f};
#pragma unroll
  for (int i = 0; i < 4; i++)
#pragma unroll
    for (int j = 0; j < 4; j++) acc[i][j] = z4;

  for (int k0 = 0; k0 < DIM; k0 += 64) {
    __syncthreads();  // protect previous iteration's LDS frag reads
#pragma unroll
    for (int h = 0; h < 2; h++) {
#pragma unroll
      for (int j = 0; j < 2; j++) {
        int ra = m0 + r0 + j * 16 + lr; ra = ra < M ? ra : M - 1;
        gl_lds16(A + (size_t)ra * DIM + k0 + h * 32 + lc,
                 (char*)sA[h] + (r0 + j * 16) * 64);
        int rb = n0 + r0 + j * 16 + lr;
        gl_lds16(BT + (size_t)rb * DIM + k0 + h * 32 + lc,
                 (char*)sB[h] + (r0 + j * 16) * 64);
      }
    }
    __builtin_amdgcn_s_waitcnt(0x0f70);  // vmcnt(0): drain gl_lds
    __syncthreads();
#pragma unroll
    for (int h = 0; h < 2; h++) {
      bf16x8 fa[4], fb[4];
#pragma unroll
      for (int i = 0; i < 4; i++) {
        fa[i] = ld8bf(sA[h] + (fm + i * 16) * 32 + ko);
        fb[i] = ld8bf(sB[h] + (fn + i * 16) * 32 + ko);
      }
#pragma unroll
      for (int i = 0; i < 4; i++)
#pragma unroll
        for (int j = 0; j < 4; j++)
          acc[i][j] = __builtin_amdgcn_mfma_f32_16x16x32_bf16(fa[i], fb[j], acc[i][j], 0, 0, 0);
    }
  }
  // epilogue: D row=(lane>>4)*4+r, col=lane&15 (verified m89/m91)
#pragma unroll
  for (int j = 0; j < 4; j++) {
    int col = n0 + nh + j * 16 + (lane & 15);
    float bvv = (mode == 0 && bias) ? bias[col] : 0.f;
#pragma unroll
    for (int i = 0; i < 4; i++) {
      int row = m0 + mh + i * 16 + (lane >> 4) * 4;
#pragma unroll
      for (int r = 0; r < 4; r++) {
        if (row + r < M) {
          float val = acc[i][j][r] + bvv;
          if (mode == 0)
            Cf[(size_t)(row + r) * DIM + col] = val;
          else
            Cb[(size_t)z * ((size_t)NH * SLEN * HD) +
               (size_t)(col >> 7) * ((size_t)SLEN * HD) +
               (size_t)(row + r) * HD + (col & 127)] = f2b(val);
        }
      }
    }
  }
}

// --------------------------------------- RMSNorm + gamma + 3D RoPE for Q / K
// In/out (in-place): Qb/Kb head-split [12][SLEN][128] bf16. Params fp32.
__global__ __launch_bounds__(256) void norm_rope(
    uint16_t* __restrict__ Qb, uint16_t* __restrict__ Kb,
    const float* __restrict__ bq, const float* __restrict__ bk,
    const float* __restrict__ gq, const float* __restrict__ gk,
    const float* __restrict__ freqs, const int* __restrict__ gsz) {
  const int s = blockIdx.x;
  const int isK = blockIdx.y;
  uint32_t* B = (uint32_t*)(isK ? Kb : Qb);
  const float2* br = (const float2*)(isK ? bk : bq);
  const float2* gr = (const float2*)(isK ? gk : gq);
  const int tid = threadIdx.x;
  float va[3], vb[3];
  float ss = 0.f;
#pragma unroll
  for (int i = 0; i < 3; i++) {
    int p = tid + i * 256;  // pair index 0..767
    int h = p >> 6, j = p & 63;
    size_t a = (size_t)h * (SLEN * 64) + (size_t)s * 64 + j;
    uint32_t u = B[a];
    float2 ub = br[p];
    float x0 = b2f((uint16_t)(u & 0xffff)) + ub.x;
    float x1 = b2f((uint16_t)(u >> 16)) + ub.y;
    va[i] = x0; vb[i] = x1; ss += x0 * x0 + x1 * x1;
  }
#pragma unroll
  for (int o = 32; o > 0; o >>= 1) ss += __shfl_down(ss, o, 64);
  __shared__ float red[4];
  if ((tid & 63) == 0) red[tid >> 6] = ss;
  __syncthreads();
  ss = red[0] + red[1] + red[2] + red[3];
  const float rr = rsqrtf(ss * (1.0f / DIM) + 1e-6f);
  const int H = gsz[1], W = gsz[2];
  const int hw = H * W;
  const int fi = s / hw, rem = s - fi * hw;
  const int hi = rem / W, wi = rem - hi * W;
#pragma unroll
  for (int i = 0; i < 3; i++) {
    int p = tid + i * 256;
    int h = p >> 6, j = p & 63;
    int prow = (j < 22) ? fi : (j < 43) ? hi : wi;  // c0=22, c3=21
    float2 f2 = ((const float2*)freqs)[prow * 64 + j];
    float2 g2 = gr[p];
    float na = va[i] * rr * g2.x;
    float nb = vb[i] * rr * g2.y;
    float ra = na * f2.x - nb * f2.y;
    float rb = na * f2.y + nb * f2.x;
    size_t a = (size_t)h * (SLEN * 64) + (size_t)s * 64 + j;
    B[a] = (uint32_t)f2b(ra) | ((uint32_t)f2b(rb) << 16);
  }
}

// ----------------- V: bias(fp32) + reformat [12][SLEN][128] -> V^T [12][128][SPAD]
__global__ __launch_bounds__(256) void v_reformat(
    const uint16_t* __restrict__ Vb, const float* __restrict__ bv,
    uint16_t* __restrict__ VT) {
  __shared__ uint16_t t[128][136];
  const int head = blockIdx.x;
  const int s0 = blockIdx.y * 128;
  const int tid = threadIdx.x;
  const int cb = (tid & 15) * 8, rb = tid >> 4;
  const uint16_t* Vh = Vb + (size_t)head * SLEN * HD;
  float bvf[8];
#pragma unroll
  for (int q = 0; q < 8; q++) bvf[q] = bv[head * HD + cb + q];
#pragma unroll
  for (int pass = 0; pass < 8; pass++) {
    int r = rb + pass * 16;
    int s = s0 + r; int sc = s < SLEN ? s : SLEN - 1;
    uint16_t u[8];
    __builtin_memcpy(u, Vh + (size_t)sc * HD + cb, 16);
#pragma unroll
    for (int q = 0; q < 8; q++) t[r][cb + q] = f2b(b2f(u[q]) + bvf[q]);
  }
  __syncthreads();
  const int sb = (tid & 15) * 8, db = tid >> 4;
#pragma unroll
  for (int pass = 0; pass < 8; pass++) {
    int d = db + pass * 16;
    uint16_t out[8] __attribute__((aligned(16)));
#pragma unroll
    for (int i2 = 0; i2 < 8; i2++) {
      int s = s0 + sb + i2;
      out[i2] = (s < SLEN) ? t[sb + i2][d] : (uint16_t)0;
    }
    size_t base = ((size_t)head * HD + d) * SPAD + s0 + sb;
    if (s0 + sb + 8 <= SLEN) {
      __builtin_memcpy(VT + base, out, 16);
    } else {
#pragma unroll
      for (int i2 = 0; i2 < 8; i2++) {
        int s = s0 + sb + i2;
        if (s < SPAD) VT[base + i2] = out[i2];
      }
    }
  }
}

// ------------------------------------------------ flash attention (bf16 MFMA)
// R17: exact R6 body (best measured: 183us, occ 28%, VGPR 84) + hoisted mask.
// Split-2 stays: halved per-block runtime doubles block turnover -> keeps CU
// residency filled + K/V L2 locality (R6 FETCH ~= unique bytes; R7 single-pass
// regressed to 218us at 17% occupancy). Mask branch is wave-uniform; only the
// last KV tile of z=1 is masked (KSPLIT/64 exact, seqlen=3900).
__global__ __launch_bounds__(256) void attn_split(
    const uint16_t* __restrict__ Q, const uint16_t* __restrict__ K,
    const uint16_t* __restrict__ VT, float* __restrict__ Op,
    float* __restrict__ Lp, const int* __restrict__ seq_lens) {
  __shared__ __align__(16) uint16_t sK[64 * 128];   // [kk][d]  16.0 KB swizzled
  __shared__ __align__(16) uint16_t sV[128 * 64];   // [d][kk]  16.0 KB swizzled
  __shared__ __align__(16) uint16_t sP[64 * 64];    // [q][kk]   8.0 KB swizzled
  const int head = blockIdx.x;
  const int q0 = blockIdx.y * 64;
  const int zz = blockIdx.z;
  const int kvbeg = zz ? KSPLIT : 0;
  const int kvend = zz ? SLEN : KSPLIT;
  const int tid = threadIdx.x;
  const int wave = tid >> 6, lane = tid & 63;
  int sl = seq_lens[0];
  const int seqlen = sl < SLEN ? sl : SLEN;
  const uint16_t* Qh = Q + (size_t)head * SLEN * HD;
  const uint16_t* Kh = K + (size_t)head * SLEN * HD;
  const uint16_t* Vh = VT + (size_t)head * HD * SPAD;

  const int fm = lane & 15;
  const int ko = (lane >> 4) * 8;
  const int kr0 = tid >> 4, kcc = (tid & 15) * 8;  // K: rows kr0+ps*16, col kcc
  const int vd0 = tid >> 3, vcc = (tid & 7) * 8;   // V: rows vd0+ps*32, col vcc

  // stage Q through sK once; pull this wave's fragments to registers
#pragma unroll
  for (int ps = 0; ps < 4; ps++) {
    int row = kr0 + ps * 16;
    int qg = q0 + row; qg = qg < SLEN ? qg : SLEN - 1;
    st8(swz256(sK, row, kcc), ld8bf(Qh + (size_t)qg * HD + kcc));
  }
  __syncthreads();
  bf16x8 aq[4];
#pragma unroll
  for (int kc = 0; kc < 4; kc++)
    aq[kc] = ld8bf(swz256(sK, wave * 16 + fm, kc * 32 + ko));

  f32x4 o[8];
  const f32x4 z4 = {0.f, 0.f, 0.f, 0.f};
#pragma unroll
  for (int j = 0; j < 8; j++) o[j] = z4;
  float l_r[4] = {0.f, 0.f, 0.f, 0.f};  // per-lane partial row sums

  const float C1 = 0.08838834764831845f * 1.4426950408889634f;  // scale*log2e
  const float C2 = 12.0f * 1.4426950408889634f;                 // M*log2e

  // prologue: prefetch first tile of this z-half into registers (T14)
  bf16x8 kr[4], vr[4];
#pragma unroll
  for (int ps = 0; ps < 4; ps++) {
    kr[ps] = ld8bf(Kh + (size_t)(kvbeg + kr0 + ps * 16) * HD + kcc);
    vr[ps] = ld8bf(Vh + (size_t)(vd0 + ps * 32) * SPAD + kvbeg + vcc);
  }

  for (int kv0 = kvbeg; kv0 < kvend; kv0 += 64) {
    __syncthreads();  // all waves done reading sK/sV (and aq on iter 0)
    // reg -> LDS (compiler inserts vmcnt wait on kr/vr here)
#pragma unroll
    for (int ps = 0; ps < 4; ps++) {
      st8(swz256(sK, kr0 + ps * 16, kcc), kr[ps]);
      st8(swz128(sV, vd0 + ps * 32, vcc), vr[ps]);
    }
    __syncthreads();
    // issue next tile's global loads NOW: latency hides under QK^T+softmax+PV
    int nv0 = kv0 + 64;
    if (nv0 < kvend) {
#pragma unroll
      for (int ps = 0; ps < 4; ps++) {
        int kg = nv0 + kr0 + ps * 16; kg = kg < SLEN ? kg : SLEN - 1;
        kr[ps] = ld8bf(Kh + (size_t)kg * HD + kcc);
        vr[ps] = ld8bf(Vh + (size_t)(vd0 + ps * 32) * SPAD + nv0 + vcc);
      }
    }

    // QK^T : 16 mfma
    f32x4 sc[4];
#pragma unroll
    for (int kk = 0; kk < 4; kk++) sc[kk] = z4;
    __builtin_amdgcn_s_setprio(1);
#pragma unroll
    for (int kc = 0; kc < 4; kc++) {
#pragma unroll
      for (int kk = 0; kk < 4; kk++) {
        bf16x8 bkf = ld8bf(swz256(sK, kk * 16 + fm, kc * 32 + ko));
        sc[kk] = __builtin_amdgcn_mfma_f32_16x16x32_bf16(aq[kc], bkf, sc[kk], 0, 0, 0);
      }
    }
    __builtin_amdgcn_s_setprio(0);
    // static-max softmax: p = exp2(s*C1 - C2); mask hoisted to a wave-uniform
    // branch (only the last KV tile can be partially masked)
    if (kv0 + 64 <= seqlen) {
#pragma unroll
      for (int kk = 0; kk < 4; kk++) {
#pragma unroll
        for (int r = 0; r < 4; r++) {
          float p = exp2f(sc[kk][r] * C1 - C2);
          l_r[r] += p;
          *swz128(sP, wave * 16 + (lane >> 4) * 4 + r, kk * 16 + fm) = f2b(p);
        }
      }
    } else {
#pragma unroll
      for (int kk = 0; kk < 4; kk++) {
        int col = kv0 + kk * 16 + fm;
        bool valid = col < seqlen;
#pragma unroll
        for (int r = 0; r < 4; r++) {
          float p = valid ? exp2f(sc[kk][r] * C1 - C2) : 0.f;
          l_r[r] += p;
          *swz128(sP, wave * 16 + (lane >> 4) * 4 + r, kk * 16 + fm) = f2b(p);
        }
      }
    }
    // PV : 16 mfma  (sP 16-row slabs are wave-private -> no barrier needed)
    __builtin_amdgcn_s_setprio(1);
#pragma unroll
    for (int kc = 0; kc < 2; kc++) {
      bf16x8 ap = ld8bf(swz128(sP, wave * 16 + fm, kc * 32 + ko));
#pragma unroll
      for (int j = 0; j < 8; j++) {
        bf16x8 bvf = ld8bf(swz128(sV, j * 16 + fm, kc * 32 + ko));
        o[j] = __builtin_amdgcn_mfma_f32_16x16x32_bf16(ap, bvf, o[j], 0, 0, 0);
      }
    }
    __builtin_amdgcn_s_setprio(0);
  }
  // reduce l across the 16-lane row group (once)
#pragma unroll
  for (int r = 0; r < 4; r++) {
#pragma unroll
    for (int off = 1; off < 16; off <<= 1) l_r[r] += __shfl_xor(l_r[r], off, 64);
  }
  // epilogue: UNSCALED f32 partials + per-row l partial
  float* Oz = Op + (size_t)zz * ((size_t)SLEN * DIM);
#pragma unroll
  for (int r = 0; r < 4; r++) {
    int row = q0 + wave * 16 + (lane >> 4) * 4 + r;
    if (row < SLEN) {
#pragma unroll
      for (int j = 0; j < 8; j++) {
        int col = head * HD + j * 16 + fm;
        Oz[(size_t)row * DIM + col] = o[j][r];
      }
      if (fm == 0) Lp[((size_t)zz * NH + head) * SLEN + row] = l_r[r];
    }
  }
}

// ------------------- combine split partials: AO = bf16((o0+o1)/(l0+l1))
__global__ __launch_bounds__(256) void combine(
    const float* __restrict__ Op, const float* __restrict__ Lp,
    uint16_t* __restrict__ AO) {
  int i = (blockIdx.x * 256 + threadIdx.x) * 8;  // SLEN*DIM divisible by 2048
  int row = i / DIM;
  int col = i - row * DIM;
  int head = col >> 7;
  float l = Lp[(size_t)head * SLEN + row] + Lp[(size_t)(NH + head) * SLEN + row];
  float inv = 1.0f / l;
  float a[8], b[8];
  __builtin_memcpy(a, Op + i, 32);
  __builtin_memcpy(b, Op + (size_t)SLEN * DIM + i, 32);
  uint16_t t[8];
#pragma unroll
  for (int q = 0; q < 8; q++) t[q] = f2b((a[q] + b[q]) * inv);
  __builtin_memcpy(AO + i, t, 16);
}

// ---------------- fallback: R1 single-pass attn (used if workspace too small)
__global__ __launch_bounds__(256) void attn(
    const uint16_t* __restrict__ Q, const uint16_t* __restrict__ K,
    const uint16_t* __restrict__ VT, uint16_t* __restrict__ O,
    const int* __restrict__ seq_lens) {
  __shared__ __align__(16) uint16_t sK[64 * SKP];
  __shared__ __align__(16) uint16_t sV[128 * SVP];
  __shared__ __align__(16) uint16_t sP[64 * SVP];
  const int head = blockIdx.x;
  const int q0 = blockIdx.y * 64;
  const int tid = threadIdx.x;
  const int wave = tid >> 6, lane = tid & 63;
  int sl = seq_lens[0];
  const int seqlen = sl < SLEN ? sl : SLEN;
  const uint16_t* Qh = Q + (size_t)head * SLEN * HD;
  const uint16_t* Kh = K + (size_t)head * SLEN * HD;
  const uint16_t* Vh = VT + (size_t)head * HD * SPAD;
  const int fm = lane & 15;
  const int ko = (lane >> 4) * 8;
  const int kr0 = tid >> 4, kcc = (tid & 15) * 8;
  const int vd0 = tid >> 3, vcc = (tid & 7) * 8;
#pragma unroll
  for (int ps = 0; ps < 4; ps++) {
    int row = kr0 + ps * 16;
    int qg = q0 + row; qg = qg < SLEN ? qg : SLEN - 1;
    st8(sK + row * SKP + kcc, ld8bf(Qh + (size_t)qg * HD + kcc));
  }
  __syncthreads();
  bf16x8 aq[4];
#pragma unroll
  for (int kc = 0; kc < 4; kc++)
    aq[kc] = ld8bf(sK + (wave * 16 + fm) * SKP + kc * 32 + ko);
  f32x4 o[8];
  const f32x4 z4 = {0.f, 0.f, 0.f, 0.f};
#pragma unroll
  for (int j = 0; j < 8; j++) o[j] = z4;
  float l_r[4] = {0.f, 0.f, 0.f, 0.f};
  const float C1 = 0.08838834764831845f * 1.4426950408889634f;
  const float C2 = 12.0f * 1.4426950408889634f;
  bf16x8 kr[4], vr[4];
#pragma unroll
  for (int ps = 0; ps < 4; ps++) {
    kr[ps] = ld8bf(Kh + (size_t)(kr0 + ps * 16) * HD + kcc);
    vr[ps] = ld8bf(Vh + (size_t)(vd0 + ps * 32) * SPAD + vcc);
  }
  for (int kv0 = 0; kv0 < SLEN; kv0 += 64) {
    __syncthreads();
#pragma unroll
    for (int ps = 0; ps < 4; ps++) {
      st8(sK + (kr0 + ps * 16) * SKP + kcc, kr[ps]);
      st8(sV + (vd0 + ps * 32) * SVP + vcc, vr[ps]);
    }
    __syncthreads();
    int nv0 = kv0 + 64;
    if (nv0 < SLEN) {
#pragma unroll
      for (int ps = 0; ps < 4; ps++) {
        int kg = nv0 + kr0 + ps * 16; kg = kg < SLEN ? kg : SLEN - 1;
        kr[ps] = ld8bf(Kh + (size_t)kg * HD + kcc);
        vr[ps] = ld8bf(Vh + (size_t)(vd0 + ps * 32) * SPAD + nv0 + vcc);
      }
    }
    f32x4 sc[4];
#pragma unroll
    for (int kk = 0; kk < 4; kk++) sc[kk] = z4;
    __builtin_amdgcn_s_setprio(1);
#pragma unroll
    for (int kc = 0; kc < 4; kc++) {
#pragma unroll
      for (int kk = 0; kk < 4; kk++) {
        bf16x8 bkf = ld8bf(sK + (kk * 16 + fm) * SKP + kc * 32 + ko);
        sc[kk] = __builtin_amdgcn_mfma_f32_16x16x32_bf16(aq[kc], bkf, sc[kk], 0, 0, 0);
      }
    }
    __builtin_amdgcn_s_setprio(0);
#pragma unroll
    for (int kk = 0; kk < 4; kk++) {
      int col = kv0 + kk * 16 + fm;
      bool valid = col < seqlen;
#pragma unroll
      for (int r = 0; r < 4; r++) {
        float p = valid ? exp2f(sc[kk][r] * C1 - C2) : 0.f;
        l_r[r] += p;
        sP[(wave * 16 + (lane >> 4) * 4 + r) * SVP + kk * 16 + fm] = f2b(p);
      }
    }
    __builtin_amdgcn_s_setprio(1);
#pragma unroll
    for (int kc = 0; kc < 2; kc++) {
      bf16x8 ap = ld8bf(sP + (wave * 16 + fm) * SVP + kc * 32 + ko);
#pragma unroll
      for (int j = 0; j < 8; j++) {
        bf16x8 bvf = ld8bf(sV + (j * 16 + fm) * SVP + kc * 32 + ko);
        o[j] = __builtin_amdgcn_mfma_f32_16x16x32_bf16(ap, bvf, o[j], 0, 0, 0);
      }
    }
    __builtin_amdgcn_s_setprio(0);
  }
#pragma unroll
  for (int r = 0; r < 4; r++) {
#pragma unroll
    for (int off = 1; off < 16; off <<= 1) l_r[r] += __shfl_xor(l_r[r], off, 64);
  }
#pragma unroll
  for (int r = 0; r < 4; r++) {
    int row = q0 + wave * 16 + (lane >> 4) * 4 + r;
    if (row < SLEN) {
      float inv = 1.0f / l_r[r];
#pragma unroll
      for (int j = 0; j < 8; j++) {
        int col = head * HD + j * 16 + fm;
        O[(size_t)row * DIM + col] = f2b(o[j][r] * inv);
      }
    }
  }
}

// ----------------------------------------------------------------- launcher
extern "C" void kernel_launch(void* const* d_in, const int* in_sizes, int n_in,
                              void* d_out, int out_size, void* d_ws, size_t ws_size,
                              hipStream_t stream) {
  const float* x      = (const float*)d_in[0];
  const int* seq_lens = (const int*)d_in[1];
  const int* gsz      = (const int*)d_in[2];
  const float* freqs  = (const float*)d_in[3];
  const float* Wq     = (const float*)d_in[4];
  const float* bq     = (const float*)d_in[5];
  const float* Wk     = (const float*)d_in[6];
  const float* bk     = (const float*)d_in[7];
  const float* Wv     = (const float*)d_in[8];
  const float* bv     = (const float*)d_in[9];
  const float* Wo     = (const float*)d_in[10];
  const float* bo     = (const float*)d_in[11];
  const float* gq     = (const float*)d_in[12];
  const float* gk     = (const float*)d_in[13];

  // workspace
  char* p = (char*)d_ws;
  uint16_t* WT4 = (uint16_t*)p; p += (size_t)4 * DIM * DIM * 2;    // 18.87 MB
  uint16_t* Qb  = (uint16_t*)p; p += (size_t)NH * SLEN * HD * 2;   // 11.98 MB
  uint16_t* Kb  = (uint16_t*)p; p += (size_t)NH * SLEN * HD * 2;   // 11.98 MB
  uint16_t* Vb  = (uint16_t*)p; p += (size_t)NH * SLEN * HD * 2;   // 11.98 MB
  uint16_t* VTb = (uint16_t*)p; p += (size_t)NH * HD * SPAD * 2;   // 11.99 MB
  float*    Opb = (float*)p;    p += (size_t)2 * SLEN * DIM * 4;   // 47.92 MB
  float*    Lpb = (float*)p;    p += (size_t)2 * NH * SLEN * 4;    //  0.37 MB
  const size_t need = (size_t)(p - (char*)d_ws);
  uint16_t* xb  = VTb;   // [SLEN][DIM] bf16 — dead before VTb written
  uint16_t* AO  = Vb;    // attn output overlays Vb (consumed by v_reformat)

  conv_x<<<dim3(2925), 256, 0, stream>>>(x, xb);
  transposeW4<<<dim3(48, 48, 4), 256, 0, stream>>>(Wq, Wk, Wv, Wo, WT4);

  // QKV batched: z selects weight slice + output third (Qb,Kb,Vb contiguous)
  gemm<<<dim3(31, 12, 3), 256, 0, stream>>>(xb, WT4, Qb, nullptr, nullptr, SLEN, 1);

  norm_rope<<<dim3(SLEN, 2), 256, 0, stream>>>(Qb, Kb, bq, bk, gq, gk, freqs, gsz);
  v_reformat<<<dim3(NH, 31), 256, 0, stream>>>(Vb, bv, VTb);

  if (ws_size >= need) {
    attn_split<<<dim3(NH, 61, 2), 256, 0, stream>>>(Qb, Kb, VTb, Opb, Lpb, seq_lens);
    combine<<<dim3(2925), 256, 0, stream>>>(Opb, Lpb, AO);
  } else {
    attn<<<dim3(NH, 61), 256, 0, stream>>>(Qb, Kb, VTb, AO, seq_lens);
  }

  gemm<<<dim3(31, 12, 1), 256, 0, stream>>>(AO, WT4 + (size_t)3 * DIM * DIM,
                                            nullptr, (float*)d_out, bo, SLEN, 0);
}

// Round 9
// 463.761 us; speedup vs baseline: 1.0809x; 1.0809x over previous
//
#include <hip/hip_runtime.h>
#include <stdint.h>

// Inputs are FP32 (proven R4-R7 pass/fail matrix); output is FP32.
#define DIM 1536
#define SLEN 3900
#define SPAD 3904   // padded V^T row stride (16B-aligned rows)
#define NH 12
#define HD 128
#define SKP 136     // fallback attn sK row stride (elems)
#define SVP 68      // fallback attn sV/sP row stride (elems)
#define KSPLIT 1984 // KV split point: 31 tiles / 30 tiles

typedef __bf16 bf16x8 __attribute__((ext_vector_type(8)));
typedef float f32x4 __attribute__((ext_vector_type(4)));

__device__ __forceinline__ float b2f(uint16_t u) {
  union { uint32_t i; float f; } x; x.i = ((uint32_t)u) << 16; return x.f;
}
// hardware RNE convert
__device__ __forceinline__ uint16_t f2b(float f) {
  union { __bf16 h; uint16_t u; } c; c.h = (__bf16)f; return c.u;
}
__device__ __forceinline__ bf16x8 ld8bf(const uint16_t* p) {
  bf16x8 r; __builtin_memcpy(&r, p, 16); return r;
}
__device__ __forceinline__ void st8(uint16_t* p, bf16x8 v) {
  __builtin_memcpy(p, &v, 16);
}
// async global->LDS, 16B/lane; LDS dest = wave-uniform base + lane*16 (m97/m104)
__device__ __forceinline__ void gl_lds16(const void* g, void* l) {
  __builtin_amdgcn_global_load_lds((__attribute__((address_space(1))) void*)(g),
                                   (__attribute__((address_space(3))) void*)(l),
                                   16, 0, 0);
}
// G4 XOR-swizzled LDS addressing (unpadded rows; byte ^= (row&7)<<4).
// 256B-row variant (sK: 128 bf16/row) and 128B-row variant (sV/sP: 64 bf16/row).
__device__ __forceinline__ uint16_t* swz256(uint16_t* b, int row, int ce) {
  return (uint16_t*)((char*)b + row * 256 + ((ce * 2) ^ ((row & 7) << 4)));
}
__device__ __forceinline__ uint16_t* swz128(uint16_t* b, int row, int ce) {
  return (uint16_t*)((char*)b + row * 128 + ((ce * 2) ^ ((row & 7) << 4)));
}

// ------------------------------------------------ x: fp32 -> bf16 (one pass)
__global__ __launch_bounds__(256) void conv_x(
    const float* __restrict__ x, uint16_t* __restrict__ xb) {
  int i = (blockIdx.x * 256 + threadIdx.x) * 8;  // n divisible by 8
  float a[8];
  __builtin_memcpy(a, x + i, 32);
  uint16_t t[8];
#pragma unroll
  for (int q = 0; q < 8; q++) t[q] = f2b(a[q]);
  __builtin_memcpy(xb + i, t, 16);
}

// --------------------- transpose all 4 W: fp32 in -> bf16^T out (z selects)
__global__ __launch_bounds__(256) void transposeW4(
    const float* __restrict__ w0, const float* __restrict__ w1,
    const float* __restrict__ w2, const float* __restrict__ w3,
    uint16_t* __restrict__ WT4) {
  __shared__ uint16_t t[32][33];
  const int z = blockIdx.z;
  const float* src = z == 0 ? w0 : z == 1 ? w1 : z == 2 ? w2 : w3;
  uint16_t* dst = WT4 + (size_t)z * DIM * DIM;
  const int bx = blockIdx.x * 32, by = blockIdx.y * 32;
  const int tx = threadIdx.x & 31, ty = threadIdx.x >> 5;  // ty 0..7
#pragma unroll
  for (int i = 0; i < 32; i += 8)
    t[ty + i][tx] = f2b(src[(size_t)(by + ty + i) * DIM + bx + tx]);
  __syncthreads();
#pragma unroll
  for (int i = 0; i < 32; i += 8)
    dst[(size_t)(bx + ty + i) * DIM + by + tx] = t[tx][ty + i];
}

// ------------------------------------------------- GEMM: C = A * BT^T (+bias)
// gl_lds staging (m97 idiom): unpadded 64B-pitch LDS (required: lane-ordered
// dest). Proven BK=32 single-buffer body (R8's BK=64 variant regressed ~20us).
// mode 1: z selects BT slice + head-split bf16 out Cb. mode 0: fp32 out + bias.
__global__ __launch_bounds__(256) void gemm(
    const uint16_t* __restrict__ A, const uint16_t* __restrict__ BT4,
    uint16_t* __restrict__ Cb, float* __restrict__ Cf,
    const float* __restrict__ bias, int M, int mode) {
  __shared__ __align__(16) uint16_t sA[128 * 32];
  __shared__ __align__(16) uint16_t sB[128 * 32];
  const int z = blockIdx.z;
  const uint16_t* BT = BT4 + (size_t)z * DIM * DIM;
  const int m0 = blockIdx.x * 128;
  const int n0 = blockIdx.y * 128;
  const int tid = threadIdx.x;
  const int wave = tid >> 6, lane = tid & 63;
  const int mh = (wave >> 1) * 64, nh = (wave & 1) * 64;
  const int lr = lane >> 2, lc = (lane & 3) * 8;  // staging row/col in 16-row slab
  const int r0 = wave * 32;                       // staging slab base row
  const int fm = mh + (lane & 15);
  const int fn = nh + (lane & 15);
  const int ko = (lane >> 4) * 8;

  f32x4 acc[4][4];
  const f32x4 z4 = {0.f, 0.f, 0.f, 0.f};
#pragma unroll
  for (int i = 0; i < 4; i++)
#pragma unroll
    for (int j = 0; j < 4; j++) acc[i][j] = z4;

  for (int k0 = 0; k0 < DIM; k0 += 32) {
    __syncthreads();  // protect previous iteration's LDS frag reads
#pragma unroll
    for (int j = 0; j < 2; j++) {
      int ra = m0 + r0 + j * 16 + lr; ra = ra < M ? ra : M - 1;
      gl_lds16(A + (size_t)ra * DIM + k0 + lc, (char*)sA + (r0 + j * 16) * 64);
      int rb = n0 + r0 + j * 16 + lr;
      gl_lds16(BT + (size_t)rb * DIM + k0 + lc, (char*)sB + (r0 + j * 16) * 64);
    }
    __builtin_amdgcn_s_waitcnt(0x0f70);  // vmcnt(0): drain gl_lds
    __syncthreads();
    bf16x8 fa[4], fb[4];
#pragma unroll
    for (int i = 0; i < 4; i++) {
      fa[i] = ld8bf(sA + (fm + i * 16) * 32 + ko);
      fb[i] = ld8bf(sB + (fn + i * 16) * 32 + ko);
    }
#pragma unroll
    for (int i = 0; i < 4; i++)
#pragma unroll
      for (int j = 0; j < 4; j++)
        acc[i][j] = __builtin_amdgcn_mfma_f32_16x16x32_bf16(fa[i], fb[j], acc[i][j], 0, 0, 0);
  }
  // epilogue: D row=(lane>>4)*4+r, col=lane&15 (verified m89/m91)
#pragma unroll
  for (int j = 0; j < 4; j++) {
    int col = n0 + nh + j * 16 + (lane & 15);
    float bvv = (mode == 0 && bias) ? bias[col] : 0.f;
#pragma unroll
    for (int i = 0; i < 4; i++) {
      int row = m0 + mh + i * 16 + (lane >> 4) * 4;
#pragma unroll
      for (int r = 0; r < 4; r++) {
        if (row + r < M) {
          float val = acc[i][j][r] + bvv;
          if (mode == 0)
            Cf[(size_t)(row + r) * DIM + col] = val;
          else
            Cb[(size_t)z * ((size_t)NH * SLEN * HD) +
               (size_t)(col >> 7) * ((size_t)SLEN * HD) +
               (size_t)(row + r) * HD + (col & 127)] = f2b(val);
        }
      }
    }
  }
}

// --------------------- RMSNorm + gamma + 3D RoPE for Q / K (+ Q pre-scale)
// In/out (in-place): Qb/Kb head-split [12][SLEN][128] bf16. Params fp32.
// R9: Q output pre-scaled by C1 = attn_scale*log2e, so attn computes
// p = exp2(sc) directly (the 2^-C2 static-max factor cancels in o/l).
__global__ __launch_bounds__(256) void norm_rope(
    uint16_t* __restrict__ Qb, uint16_t* __restrict__ Kb,
    const float* __restrict__ bq, const float* __restrict__ bk,
    const float* __restrict__ gq, const float* __restrict__ gk,
    const float* __restrict__ freqs, const int* __restrict__ gsz) {
  const int s = blockIdx.x;
  const int isK = blockIdx.y;
  uint32_t* B = (uint32_t*)(isK ? Kb : Qb);
  const float2* br = (const float2*)(isK ? bk : bq);
  const float2* gr = (const float2*)(isK ? gk : gq);
  const int tid = threadIdx.x;
  float va[3], vb[3];
  float ss = 0.f;
#pragma unroll
  for (int i = 0; i < 3; i++) {
    int p = tid + i * 256;  // pair index 0..767
    int h = p >> 6, j = p & 63;
    size_t a = (size_t)h * (SLEN * 64) + (size_t)s * 64 + j;
    uint32_t u = B[a];
    float2 ub = br[p];
    float x0 = b2f((uint16_t)(u & 0xffff)) + ub.x;
    float x1 = b2f((uint16_t)(u >> 16)) + ub.y;
    va[i] = x0; vb[i] = x1; ss += x0 * x0 + x1 * x1;
  }
#pragma unroll
  for (int o = 32; o > 0; o >>= 1) ss += __shfl_down(ss, o, 64);
  __shared__ float red[4];
  if ((tid & 63) == 0) red[tid >> 6] = ss;
  __syncthreads();
  ss = red[0] + red[1] + red[2] + red[3];
  float rr = rsqrtf(ss * (1.0f / DIM) + 1e-6f);
  if (!isK) rr *= 0.08838834764831845f * 1.4426950408889634f;  // C1 into Q
  const int H = gsz[1], W = gsz[2];
  const int hw = H * W;
  const int fi = s / hw, rem = s - fi * hw;
  const int hi = rem / W, wi = rem - hi * W;
#pragma unroll
  for (int i = 0; i < 3; i++) {
    int p = tid + i * 256;
    int h = p >> 6, j = p & 63;
    int prow = (j < 22) ? fi : (j < 43) ? hi : wi;  // c0=22, c3=21
    float2 f2 = ((const float2*)freqs)[prow * 64 + j];
    float2 g2 = gr[p];
    float na = va[i] * rr * g2.x;
    float nb = vb[i] * rr * g2.y;
    float ra = na * f2.x - nb * f2.y;
    float rb = na * f2.y + nb * f2.x;
    size_t a = (size_t)h * (SLEN * 64) + (size_t)s * 64 + j;
    B[a] = (uint32_t)f2b(ra) | ((uint32_t)f2b(rb) << 16);
  }
}

// ----------------- V: bias(fp32) + reformat [12][SLEN][128] -> V^T [12][128][SPAD]
__global__ __launch_bounds__(256) void v_reformat(
    const uint16_t* __restrict__ Vb, const float* __restrict__ bv,
    uint16_t* __restrict__ VT) {
  __shared__ uint16_t t[128][136];
  const int head = blockIdx.x;
  const int s0 = blockIdx.y * 128;
  const int tid = threadIdx.x;
  const int cb = (tid & 15) * 8, rb = tid >> 4;
  const uint16_t* Vh = Vb + (size_t)head * SLEN * HD;
  float bvf[8];
#pragma unroll
  for (int q = 0; q < 8; q++) bvf[q] = bv[head * HD + cb + q];
#pragma unroll
  for (int pass = 0; pass < 8; pass++) {
    int r = rb + pass * 16;
    int s = s0 + r; int sc = s < SLEN ? s : SLEN - 1;
    uint16_t u[8];
    __builtin_memcpy(u, Vh + (size_t)sc * HD + cb, 16);
#pragma unroll
    for (int q = 0; q < 8; q++) t[r][cb + q] = f2b(b2f(u[q]) + bvf[q]);
  }
  __syncthreads();
  const int sb = (tid & 15) * 8, db = tid >> 4;
#pragma unroll
  for (int pass = 0; pass < 8; pass++) {
    int d = db + pass * 16;
    uint16_t out[8] __attribute__((aligned(16)));
#pragma unroll
    for (int i2 = 0; i2 < 8; i2++) {
      int s = s0 + sb + i2;
      out[i2] = (s < SLEN) ? t[sb + i2][d] : (uint16_t)0;
    }
    size_t base = ((size_t)head * HD + d) * SPAD + s0 + sb;
    if (s0 + sb + 8 <= SLEN) {
      __builtin_memcpy(VT + base, out, 16);
    } else {
#pragma unroll
      for (int i2 = 0; i2 < 8; i2++) {
        int s = s0 + sb + i2;
        if (s < SPAD) VT[base + i2] = out[i2];
      }
    }
  }
}

// ------------------------------------------------ flash attention (bf16 MFMA)
// R9: EXACT R6 body (best measured: 183us, occ 28%, VGPR 84) with the only
// change being p = exp2(sc) (Q pre-scaled by C1 in norm_rope; 2^-C2 cancels
// in o/l). Per-element mask kept (R8's hoist perturbed codegen, -9%).
__global__ __launch_bounds__(256) void attn_split(
    const uint16_t* __restrict__ Q, const uint16_t* __restrict__ K,
    const uint16_t* __restrict__ VT, float* __restrict__ Op,
    float* __restrict__ Lp, const int* __restrict__ seq_lens) {
  __shared__ __align__(16) uint16_t sK[64 * 128];   // [kk][d]  16.0 KB swizzled
  __shared__ __align__(16) uint16_t sV[128 * 64];   // [d][kk]  16.0 KB swizzled
  __shared__ __align__(16) uint16_t sP[64 * 64];    // [q][kk]   8.0 KB swizzled
  const int head = blockIdx.x;
  const int q0 = blockIdx.y * 64;
  const int zz = blockIdx.z;
  const int kvbeg = zz ? KSPLIT : 0;
  const int kvend = zz ? SLEN : KSPLIT;
  const int tid = threadIdx.x;
  const int wave = tid >> 6, lane = tid & 63;
  int sl = seq_lens[0];
  const int seqlen = sl < SLEN ? sl : SLEN;
  const uint16_t* Qh = Q + (size_t)head * SLEN * HD;
  const uint16_t* Kh = K + (size_t)head * SLEN * HD;
  const uint16_t* Vh = VT + (size_t)head * HD * SPAD;

  const int fm = lane & 15;
  const int ko = (lane >> 4) * 8;
  const int kr0 = tid >> 4, kcc = (tid & 15) * 8;  // K: rows kr0+ps*16, col kcc
  const int vd0 = tid >> 3, vcc = (tid & 7) * 8;   // V: rows vd0+ps*32, col vcc

  // stage Q through sK once; pull this wave's fragments to registers
#pragma unroll
  for (int ps = 0; ps < 4; ps++) {
    int row = kr0 + ps * 16;
    int qg = q0 + row; qg = qg < SLEN ? qg : SLEN - 1;
    st8(swz256(sK, row, kcc), ld8bf(Qh + (size_t)qg * HD + kcc));
  }
  __syncthreads();
  bf16x8 aq[4];
#pragma unroll
  for (int kc = 0; kc < 4; kc++)
    aq[kc] = ld8bf(swz256(sK, wave * 16 + fm, kc * 32 + ko));

  f32x4 o[8];
  const f32x4 z4 = {0.f, 0.f, 0.f, 0.f};
#pragma unroll
  for (int j = 0; j < 8; j++) o[j] = z4;
  float l_r[4] = {0.f, 0.f, 0.f, 0.f};  // per-lane partial row sums

  // prologue: prefetch first tile of this z-half into registers (T14)
  bf16x8 kr[4], vr[4];
#pragma unroll
  for (int ps = 0; ps < 4; ps++) {
    kr[ps] = ld8bf(Kh + (size_t)(kvbeg + kr0 + ps * 16) * HD + kcc);
    vr[ps] = ld8bf(Vh + (size_t)(vd0 + ps * 32) * SPAD + kvbeg + vcc);
  }

  for (int kv0 = kvbeg; kv0 < kvend; kv0 += 64) {
    __syncthreads();  // all waves done reading sK/sV (and aq on iter 0)
    // reg -> LDS (compiler inserts vmcnt wait on kr/vr here)
#pragma unroll
    for (int ps = 0; ps < 4; ps++) {
      st8(swz256(sK, kr0 + ps * 16, kcc), kr[ps]);
      st8(swz128(sV, vd0 + ps * 32, vcc), vr[ps]);
    }
    __syncthreads();
    // issue next tile's global loads NOW: latency hides under QK^T+softmax+PV
    int nv0 = kv0 + 64;
    if (nv0 < kvend) {
#pragma unroll
      for (int ps = 0; ps < 4; ps++) {
        int kg = nv0 + kr0 + ps * 16; kg = kg < SLEN ? kg : SLEN - 1;
        kr[ps] = ld8bf(Kh + (size_t)kg * HD + kcc);
        vr[ps] = ld8bf(Vh + (size_t)(vd0 + ps * 32) * SPAD + nv0 + vcc);
      }
    }

    // QK^T : 16 mfma
    f32x4 sc[4];
#pragma unroll
    for (int kk = 0; kk < 4; kk++) sc[kk] = z4;
    __builtin_amdgcn_s_setprio(1);
#pragma unroll
    for (int kc = 0; kc < 4; kc++) {
#pragma unroll
      for (int kk = 0; kk < 4; kk++) {
        bf16x8 bkf = ld8bf(swz256(sK, kk * 16 + fm, kc * 32 + ko));
        sc[kk] = __builtin_amdgcn_mfma_f32_16x16x32_bf16(aq[kc], bkf, sc[kk], 0, 0, 0);
      }
    }
    __builtin_amdgcn_s_setprio(0);
    // softmax: p = exp2(sc) (Q pre-scaled; static-max factor cancels in o/l)
#pragma unroll
    for (int kk = 0; kk < 4; kk++) {
      int col = kv0 + kk * 16 + fm;
      bool valid = col < seqlen;
#pragma unroll
      for (int r = 0; r < 4; r++) {
        float p = valid ? exp2f(sc[kk][r]) : 0.f;
        l_r[r] += p;
        *swz128(sP, wave * 16 + (lane >> 4) * 4 + r, kk * 16 + fm) = f2b(p);
      }
    }
    // PV : 16 mfma  (sP 16-row slabs are wave-private -> no barrier needed)
    __builtin_amdgcn_s_setprio(1);
#pragma unroll
    for (int kc = 0; kc < 2; kc++) {
      bf16x8 ap = ld8bf(swz128(sP, wave * 16 + fm, kc * 32 + ko));
#pragma unroll
      for (int j = 0; j < 8; j++) {
        bf16x8 bvf = ld8bf(swz128(sV, j * 16 + fm, kc * 32 + ko));
        o[j] = __builtin_amdgcn_mfma_f32_16x16x32_bf16(ap, bvf, o[j], 0, 0, 0);
      }
    }
    __builtin_amdgcn_s_setprio(0);
  }
  // reduce l across the 16-lane row group (once)
#pragma unroll
  for (int r = 0; r < 4; r++) {
#pragma unroll
    for (int off = 1; off < 16; off <<= 1) l_r[r] += __shfl_xor(l_r[r], off, 64);
  }
  // epilogue: UNSCALED f32 partials + per-row l partial
  float* Oz = Op + (size_t)zz * ((size_t)SLEN * DIM);
#pragma unroll
  for (int r = 0; r < 4; r++) {
    int row = q0 + wave * 16 + (lane >> 4) * 4 + r;
    if (row < SLEN) {
#pragma unroll
      for (int j = 0; j < 8; j++) {
        int col = head * HD + j * 16 + fm;
        Oz[(size_t)row * DIM + col] = o[j][r];
      }
      if (fm == 0) Lp[((size_t)zz * NH + head) * SLEN + row] = l_r[r];
    }
  }
}

// ------------------- combine split partials: AO = bf16((o0+o1)/(l0+l1))
__global__ __launch_bounds__(256) void combine(
    const float* __restrict__ Op, const float* __restrict__ Lp,
    uint16_t* __restrict__ AO) {
  int i = (blockIdx.x * 256 + threadIdx.x) * 8;  // SLEN*DIM divisible by 2048
  int row = i / DIM;
  int col = i - row * DIM;
  int head = col >> 7;
  float l = Lp[(size_t)head * SLEN + row] + Lp[(size_t)(NH + head) * SLEN + row];
  float inv = 1.0f / l;
  float a[8], b[8];
  __builtin_memcpy(a, Op + i, 32);
  __builtin_memcpy(b, Op + (size_t)SLEN * DIM + i, 32);
  uint16_t t[8];
#pragma unroll
  for (int q = 0; q < 8; q++) t[q] = f2b((a[q] + b[q]) * inv);
  __builtin_memcpy(AO + i, t, 16);
}

// ---------------- fallback: single-pass attn (used if workspace too small)
__global__ __launch_bounds__(256) void attn(
    const uint16_t* __restrict__ Q, const uint16_t* __restrict__ K,
    const uint16_t* __restrict__ VT, uint16_t* __restrict__ O,
    const int* __restrict__ seq_lens) {
  __shared__ __align__(16) uint16_t sK[64 * SKP];
  __shared__ __align__(16) uint16_t sV[128 * SVP];
  __shared__ __align__(16) uint16_t sP[64 * SVP];
  const int head = blockIdx.x;
  const int q0 = blockIdx.y * 64;
  const int tid = threadIdx.x;
  const int wave = tid >> 6, lane = tid & 63;
  int sl = seq_lens[0];
  const int seqlen = sl < SLEN ? sl : SLEN;
  const uint16_t* Qh = Q + (size_t)head * SLEN * HD;
  const uint16_t* Kh = K + (size_t)head * SLEN * HD;
  const uint16_t* Vh = VT + (size_t)head * HD * SPAD;
  const int fm = lane & 15;
  const int ko = (lane >> 4) * 8;
  const int kr0 = tid >> 4, kcc = (tid & 15) * 8;
  const int vd0 = tid >> 3, vcc = (tid & 7) * 8;
#pragma unroll
  for (int ps = 0; ps < 4; ps++) {
    int row = kr0 + ps * 16;
    int qg = q0 + row; qg = qg < SLEN ? qg : SLEN - 1;
    st8(sK + row * SKP + kcc, ld8bf(Qh + (size_t)qg * HD + kcc));
  }
  __syncthreads();
  bf16x8 aq[4];
#pragma unroll
  for (int kc = 0; kc < 4; kc++)
    aq[kc] = ld8bf(sK + (wave * 16 + fm) * SKP + kc * 32 + ko);
  f32x4 o[8];
  const f32x4 z4 = {0.f, 0.f, 0.f, 0.f};
#pragma unroll
  for (int j = 0; j < 8; j++) o[j] = z4;
  float l_r[4] = {0.f, 0.f, 0.f, 0.f};
  bf16x8 kr[4], vr[4];
#pragma unroll
  for (int ps = 0; ps < 4; ps++) {
    kr[ps] = ld8bf(Kh + (size_t)(kr0 + ps * 16) * HD + kcc);
    vr[ps] = ld8bf(Vh + (size_t)(vd0 + ps * 32) * SPAD + vcc);
  }
  for (int kv0 = 0; kv0 < SLEN; kv0 += 64) {
    __syncthreads();
#pragma unroll
    for (int ps = 0; ps < 4; ps++) {
      st8(sK + (kr0 + ps * 16) * SKP + kcc, kr[ps]);
      st8(sV + (vd0 + ps * 32) * SVP + vcc, vr[ps]);
    }
    __syncthreads();
    int nv0 = kv0 + 64;
    if (nv0 < SLEN) {
#pragma unroll
      for (int ps = 0; ps < 4; ps++) {
        int kg = nv0 + kr0 + ps * 16; kg = kg < SLEN ? kg : SLEN - 1;
        kr[ps] = ld8bf(Kh + (size_t)kg * HD + kcc);
        vr[ps] = ld8bf(Vh + (size_t)(vd0 + ps * 32) * SPAD + nv0 + vcc);
      }
    }
    f32x4 sc[4];
#pragma unroll
    for (int kk = 0; kk < 4; kk++) sc[kk] = z4;
    __builtin_amdgcn_s_setprio(1);
#pragma unroll
    for (int kc = 0; kc < 4; kc++) {
#pragma unroll
      for (int kk = 0; kk < 4; kk++) {
        bf16x8 bkf = ld8bf(sK + (kk * 16 + fm) * SKP + kc * 32 + ko);
        sc[kk] = __builtin_amdgcn_mfma_f32_16x16x32_bf16(aq[kc], bkf, sc[kk], 0, 0, 0);
      }
    }
    __builtin_amdgcn_s_setprio(0);
#pragma unroll
    for (int kk = 0; kk < 4; kk++) {
      int col = kv0 + kk * 16 + fm;
      bool valid = col < seqlen;
#pragma unroll
      for (int r = 0; r < 4; r++) {
        float p = valid ? exp2f(sc[kk][r]) : 0.f;
        l_r[r] += p;
        sP[(wave * 16 + (lane >> 4) * 4 + r) * SVP + kk * 16 + fm] = f2b(p);
      }
    }
    __builtin_amdgcn_s_setprio(1);
#pragma unroll
    for (int kc = 0; kc < 2; kc++) {
      bf16x8 ap = ld8bf(sP + (wave * 16 + fm) * SVP + kc * 32 + ko);
#pragma unroll
      for (int j = 0; j < 8; j++) {
        bf16x8 bvf = ld8bf(sV + (j * 16 + fm) * SVP + kc * 32 + ko);
        o[j] = __builtin_amdgcn_mfma_f32_16x16x32_bf16(ap, bvf, o[j], 0, 0, 0);
      }
    }
    __builtin_amdgcn_s_setprio(0);
  }
#pragma unroll
  for (int r = 0; r < 4; r++) {
#pragma unroll
    for (int off = 1; off < 16; off <<= 1) l_r[r] += __shfl_xor(l_r[r], off, 64);
  }
#pragma unroll
  for (int r = 0; r < 4; r++) {
    int row = q0 + wave * 16 + (lane >> 4) * 4 + r;
    if (row < SLEN) {
      float inv = 1.0f / l_r[r];
#pragma unroll
      for (int j = 0; j < 8; j++) {
        int col = head * HD + j * 16 + fm;
        O[(size_t)row * DIM + col] = f2b(o[j][r] * inv);
      }
    }
  }
}

// ----------------------------------------------------------------- launcher
extern "C" void kernel_launch(void* const* d_in, const int* in_sizes, int n_in,
                              void* d_out, int out_size, void* d_ws, size_t ws_size,
                              hipStream_t stream) {
  const float* x      = (const float*)d_in[0];
  const int* seq_lens = (const int*)d_in[1];
  const int* gsz      = (const int*)d_in[2];
  const float* freqs  = (const float*)d_in[3];
  const float* Wq     = (const float*)d_in[4];
  const float* bq     = (const float*)d_in[5];
  const float* Wk     = (const float*)d_in[6];
  const float* bk     = (const float*)d_in[7];
  const float* Wv     = (const float*)d_in[8];
  const float* bv     = (const float*)d_in[9];
  const float* Wo     = (const float*)d_in[10];
  const float* bo     = (const float*)d_in[11];
  const float* gq     = (const float*)d_in[12];
  const float* gk     = (const float*)d_in[13];

  // workspace
  char* p = (char*)d_ws;
  uint16_t* WT4 = (uint16_t*)p; p += (size_t)4 * DIM * DIM * 2;    // 18.87 MB
  uint16_t* Qb  = (uint16_t*)p; p += (size_t)NH * SLEN * HD * 2;   // 11.98 MB
  uint16_t* Kb  = (uint16_t*)p; p += (size_t)NH * SLEN * HD * 2;   // 11.98 MB
  uint16_t* Vb  = (uint16_t*)p; p += (size_t)NH * SLEN * HD * 2;   // 11.98 MB
  uint16_t* VTb = (uint16_t*)p; p += (size_t)NH * HD * SPAD * 2;   // 11.99 MB
  float*    Opb = (float*)p;    p += (size_t)2 * SLEN * DIM * 4;   // 47.92 MB
  float*    Lpb = (float*)p;    p += (size_t)2 * NH * SLEN * 4;    //  0.37 MB
  const size_t need = (size_t)(p - (char*)d_ws);
  uint16_t* xb  = VTb;   // [SLEN][DIM] bf16 — dead before VTb written
  uint16_t* AO  = Vb;    // attn output overlays Vb (consumed by v_reformat)

  conv_x<<<dim3(2925), 256, 0, stream>>>(x, xb);
  transposeW4<<<dim3(48, 48, 4), 256, 0, stream>>>(Wq, Wk, Wv, Wo, WT4);

  // QKV batched: z selects weight slice + output third (Qb,Kb,Vb contiguous)
  gemm<<<dim3(31, 12, 3), 256, 0, stream>>>(xb, WT4, Qb, nullptr, nullptr, SLEN, 1);

  norm_rope<<<dim3(SLEN, 2), 256, 0, stream>>>(Qb, Kb, bq, bk, gq, gk, freqs, gsz);
  v_reformat<<<dim3(NH, 31), 256, 0, stream>>>(Vb, bv, VTb);

  if (ws_size >= need) {
    attn_split<<<dim3(NH, 61, 2), 256, 0, stream>>>(Qb, Kb, VTb, Opb, Lpb, seq_lens);
    combine<<<dim3(2925), 256, 0, stream>>>(Opb, Lpb, AO);
  } else {
    attn<<<dim3(NH, 61), 256, 0, stream>>>(Qb, Kb, VTb, AO, seq_lens);
  }

  gemm<<<dim3(31, 12, 1), 256, 0, stream>>>(AO, WT4 + (size_t)3 * DIM * DIM,
                                            nullptr, (float*)d_out, bo, SLEN, 0);
}